// Round 1
// baseline (5998.190 us; speedup 1.0000x reference)
//
#include <hip/hip_runtime.h>
#include <hip/hip_bf16.h>

typedef float f32x4 __attribute__((ext_vector_type(4)));
typedef __bf16 bf16x8 __attribute__((ext_vector_type(8)));
typedef unsigned short ushort_t;

__device__ __forceinline__ unsigned short f2bf(float f) {
    unsigned int u = __builtin_bit_cast(unsigned int, f);
    u += 0x7fffu + ((u >> 16) & 1u);
    return (unsigned short)(u >> 16);
}

#define GCAST(p) ((const __attribute__((address_space(1))) void*)(p))
#define LCAST(p) ((__attribute__((address_space(3))) void*)(p))

// Swizzled LDS read of 8 bf16 from a [64][64] bf16 tile (128B rows).
// Logical (row, bytecol) -> physical bytecol ^ ((row&7)<<4).
// Turns the 16-way same-bank-group conflict of 128B-stride rows into the
// optimal 8-dwords-per-bank pattern (T2, §6 G4).
__device__ __forceinline__ bf16x8 ldsw(const unsigned short* T, int row, int bcol) {
    return *reinterpret_cast<const bf16x8*>(
        reinterpret_cast<const char*>(T) + row * 128 + (bcol ^ ((row & 7) << 4)));
}

// ---------------------------------------------------------------------------
// Per-layer weight conversion: fp32 -> bf16 into wbf.
// Segments (float4 units): qkv 786432 | out 262144 | w1 1048576 | w2 1048576
// ---------------------------------------------------------------------------
__global__ __launch_bounds__(256) void convert_weights_kernel(
    const float* __restrict__ qw, const float* __restrict__ ow,
    const float* __restrict__ w1, const float* __restrict__ w2,
    unsigned short* __restrict__ dst)
{
    int i = blockIdx.x * 256 + threadIdx.x;     // 0..3145727 (float4 idx)
    const float* src; int off;
    if (i < 786432)       { src = qw; off = i; }
    else if (i < 1048576) { src = ow; off = i - 786432; }
    else if (i < 2097152) { src = w1; off = i - 1048576; }
    else                  { src = w2; off = i - 2097152; }
    float4 v = ((const float4*)src)[off];
    ushort4 u;
    u.x = f2bf(v.x); u.y = f2bf(v.y); u.z = f2bf(v.z); u.w = f2bf(v.w);
    ((ushort4*)dst)[i] = u;
}

// ---------------------------------------------------------------------------
// GEMM: C[M,N] = A[M,K] @ W[N,K]^T + bias[N]; A,W bf16; C fp32 or bf16.
// 256 threads (4 waves), tile 128x128, BK=64, global_load_lds staging.
// (LDS left un-swizzled deliberately: T2 measured NULL on 2-phase 128² GEMM.)
// ---------------------------------------------------------------------------
__global__ __launch_bounds__(256) void gemm_kernel(
    const unsigned short* __restrict__ A, const unsigned short* __restrict__ W,
    const float* __restrict__ bias, void* __restrict__ Cout,
    int N, int K, int relu, int out_bf16)
{
    __shared__ alignas(16) unsigned short As[128][64];
    __shared__ alignas(16) unsigned short Bs[128][64];

    const int tid  = threadIdx.x;
    const int bn   = blockIdx.x, bm = blockIdx.y;
    const int wave = tid >> 6, lane = tid & 63;
    const int wm   = (wave >> 1) * 64, wn = (wave & 1) * 64;
    const int l15  = lane & 15, quad = lane >> 4;
    const int srow = lane >> 3;            // 0..7
    const int scol = (lane & 7) * 8;       // bf16 element col, 16B chunks

    f32x4 acc[4][4];
#pragma unroll
    for (int i = 0; i < 4; i++)
#pragma unroll
        for (int j = 0; j < 4; j++) acc[i][j] = f32x4{0.f, 0.f, 0.f, 0.f};

    const unsigned short* Abase = A + (size_t)(bm * 128) * K;
    const unsigned short* Wbase = W + (size_t)(bn * 128) * K;

    for (int k0 = 0; k0 < K; k0 += 64) {
        __syncthreads();
#pragma unroll
        for (int i = 0; i < 4; i++) {
            int r0 = (i * 4 + wave) * 8;   // wave-uniform base row
            __builtin_amdgcn_global_load_lds(
                GCAST(&Abase[(size_t)(r0 + srow) * K + k0 + scol]),
                LCAST(&As[r0][0]), 16, 0, 0);
            __builtin_amdgcn_global_load_lds(
                GCAST(&Wbase[(size_t)(r0 + srow) * K + k0 + scol]),
                LCAST(&Bs[r0][0]), 16, 0, 0);
        }
        __syncthreads();

#pragma unroll
        for (int ks = 0; ks < 2; ks++) {
            bf16x8 a[4], b[4];
#pragma unroll
            for (int mt = 0; mt < 4; mt++)
                a[mt] = *reinterpret_cast<const bf16x8*>(&As[wm + mt * 16 + l15][ks * 32 + quad * 8]);
#pragma unroll
            for (int nt = 0; nt < 4; nt++)
                b[nt] = *reinterpret_cast<const bf16x8*>(&Bs[wn + nt * 16 + l15][ks * 32 + quad * 8]);
#pragma unroll
            for (int mt = 0; mt < 4; mt++)
#pragma unroll
                for (int nt = 0; nt < 4; nt++)
                    acc[mt][nt] = __builtin_amdgcn_mfma_f32_16x16x32_bf16(
                        a[mt], b[nt], acc[mt][nt], 0, 0, 0);
        }
    }

    float* Cf = (float*)Cout;
    unsigned short* Cb = (unsigned short*)Cout;
#pragma unroll
    for (int nt = 0; nt < 4; nt++) {
        int gn = bn * 128 + wn + nt * 16 + l15;
        float bv = bias[gn];
#pragma unroll
        for (int mt = 0; mt < 4; mt++) {
            int gm0 = bm * 128 + wm + mt * 16 + quad * 4;
#pragma unroll
            for (int r = 0; r < 4; r++) {
                float v = acc[mt][nt][r] + bv;
                if (relu) v = fmaxf(v, 0.f);
                if (out_bf16) Cb[(size_t)(gm0 + r) * N + gn] = f2bf(v);
                else          Cf[(size_t)(gm0 + r) * N + gn] = v;
            }
        }
    }
}

// ---------------------------------------------------------------------------
// Flash attention, causal. One block = (b, h, 64-row q tile). 256 threads.
// qkv: [B*S, 3072] bf16.  ctx out: [B*S, 1024] bf16.
// All four LDS tiles XOR-swizzled (byte ^= (row&7)<<4):
//  - Q/K staged via global_load_lds with PRE-SWIZZLED GLOBAL SOURCE (LDS dest
//    stays linear, m173 pattern); Vt/Ps reg-staged with swizzled write addrs;
//    every fragment read uses ldsw(). Both-sides-or-neither (rule #21).
// ---------------------------------------------------------------------------
__global__ __launch_bounds__(256) void attn_kernel(
    const unsigned short* __restrict__ qkv, unsigned short* __restrict__ ctx)
{
    const int qt = blockIdx.x;          // 0..15
    const int bh = blockIdx.y;          // 0..63
    const int b  = bh >> 4, h = bh & 15;
    const int tid = threadIdx.x, wave = tid >> 6, lane = tid & 63;
    const int l15 = lane & 15, quad = lane >> 4;
    const int srow = lane >> 3;
    // pre-swizzled source column: lane (srow, c) loads global chunk c^srow so
    // that linear gload_lds dest yields LDS[row][chunk ^ (row&7)]
    const int scolz = ((lane & 7) ^ srow) * 8;
    const float scale = 0.125f;         // 1/sqrt(64)

    __shared__ alignas(16) unsigned short Qs[64][64];
    __shared__ alignas(16) unsigned short Ks[64][64];
    __shared__ alignas(16) unsigned short Vt[64][64];  // [d][k], swizzled
    __shared__ alignas(16) unsigned short Ps[64][64];

    const unsigned short* qbase = qkv + (size_t)(b * 1024 + qt * 64) * 3072 + h * 64;
#pragma unroll
    for (int i = 0; i < 2; i++) {
        int r0 = (i * 4 + wave) * 8;
        __builtin_amdgcn_global_load_lds(
            GCAST(&qbase[(size_t)(r0 + srow) * 3072 + scolz]),
            LCAST(&Qs[r0][0]), 16, 0, 0);
    }

    f32x4 O[4];
#pragma unroll
    for (int dt = 0; dt < 4; dt++) O[dt] = f32x4{0.f, 0.f, 0.f, 0.f};
    float m_run[4], l_run[4];
#pragma unroll
    for (int r = 0; r < 4; r++) { m_run[r] = -__builtin_inff(); l_run[r] = 0.f; }

    const int q_row_base = qt * 64 + wave * 16;

    for (int j = 0; j <= qt; j++) {
        __syncthreads();
        const unsigned short* kbase = qkv + (size_t)(b * 1024 + j * 64) * 3072 + 1024 + h * 64;
        const unsigned short* vbase = qkv + (size_t)(b * 1024 + j * 64) * 3072 + 2048 + h * 64;
#pragma unroll
        for (int i = 0; i < 2; i++) {
            int r0 = (i * 4 + wave) * 8;
            __builtin_amdgcn_global_load_lds(
                GCAST(&kbase[(size_t)(r0 + srow) * 3072 + scolz]),
                LCAST(&Ks[r0][0]), 16, 0, 0);
        }
#pragma unroll
        for (int i = 0; i < 4; i++) {
            int idx = tid + i * 256;
            int k = idx >> 4, c4 = (idx & 15) * 4;
            ushort4 vv = *(const ushort4*)&vbase[(size_t)k * 3072 + c4];
            char* vt = (char*)Vt;
            int klo = (k & 7) * 2;          // byte offset within 16B chunk
            int kch = (k >> 3) << 4;        // chunk byte base
            const unsigned short* vp = (const unsigned short*)&vv;
#pragma unroll
            for (int j2 = 0; j2 < 4; j2++) {
                int d = c4 + j2;
                *(unsigned short*)(vt + d * 128 + ((kch ^ ((d & 7) << 4)) | klo)) = vp[j2];
            }
        }
        __syncthreads();

        // S = Q K^T
        f32x4 Sc[4];
#pragma unroll
        for (int nt = 0; nt < 4; nt++) Sc[nt] = f32x4{0.f, 0.f, 0.f, 0.f};
        __builtin_amdgcn_s_setprio(1);
#pragma unroll
        for (int ks = 0; ks < 2; ks++) {
            bf16x8 aq = ldsw(&Qs[0][0], wave * 16 + l15, ks * 64 + quad * 16);
#pragma unroll
            for (int nt = 0; nt < 4; nt++) {
                bf16x8 bk = ldsw(&Ks[0][0], nt * 16 + l15, ks * 64 + quad * 16);
                Sc[nt] = __builtin_amdgcn_mfma_f32_16x16x32_bf16(aq, bk, Sc[nt], 0, 0, 0);
            }
        }
        __builtin_amdgcn_s_setprio(0);

#pragma unroll
        for (int nt = 0; nt < 4; nt++)
#pragma unroll
            for (int r = 0; r < 4; r++) Sc[nt][r] *= scale;

        if (j == qt) {   // causal mask only touches the diagonal tile
#pragma unroll
            for (int r = 0; r < 4; r++) {
                int qg = q_row_base + quad * 4 + r;
#pragma unroll
                for (int nt = 0; nt < 4; nt++) {
                    int kg = j * 64 + nt * 16 + l15;
                    if (kg > qg) Sc[nt][r] = -__builtin_inff();
                }
            }
        }

        float alpha[4];
#pragma unroll
        for (int r = 0; r < 4; r++) {
            float mx = -__builtin_inff();
#pragma unroll
            for (int nt = 0; nt < 4; nt++) mx = fmaxf(mx, Sc[nt][r]);
#pragma unroll
            for (int off = 1; off < 16; off <<= 1) mx = fmaxf(mx, __shfl_xor(mx, off));
            float mnew = fmaxf(m_run[r], mx);
            alpha[r] = __expf(m_run[r] - mnew);
            m_run[r] = mnew;
        }

#pragma unroll
        for (int r = 0; r < 4; r++) {
            float sum = 0.f;
#pragma unroll
            for (int nt = 0; nt < 4; nt++) {
                float p = __expf(Sc[nt][r] - m_run[r]);
                Sc[nt][r] = p;
                sum += p;
            }
#pragma unroll
            for (int off = 1; off < 16; off <<= 1) sum += __shfl_xor(sum, off);
            l_run[r] = l_run[r] * alpha[r] + sum;
        }

#pragma unroll
        for (int dt = 0; dt < 4; dt++)
#pragma unroll
            for (int r = 0; r < 4; r++) O[dt][r] *= alpha[r];

        {
            char* ps = (char*)Ps;
#pragma unroll
            for (int nt = 0; nt < 4; nt++)
#pragma unroll
                for (int r = 0; r < 4; r++) {
                    int row = wave * 16 + quad * 4 + r;
                    int col = nt * 16 + l15;
                    *(unsigned short*)(ps + row * 128 + ((col * 2) ^ ((row & 7) << 4)))
                        = f2bf(Sc[nt][r]);
                }
        }

        __builtin_amdgcn_s_setprio(1);
#pragma unroll
        for (int ks = 0; ks < 2; ks++) {
            bf16x8 ap = ldsw(&Ps[0][0], wave * 16 + l15, ks * 64 + quad * 16);
#pragma unroll
            for (int dt = 0; dt < 4; dt++) {
                bf16x8 bv = ldsw(&Vt[0][0], dt * 16 + l15, ks * 64 + quad * 16);
                O[dt] = __builtin_amdgcn_mfma_f32_16x16x32_bf16(ap, bv, O[dt], 0, 0, 0);
            }
        }
        __builtin_amdgcn_s_setprio(0);
    }

    unsigned short* obase = ctx + (size_t)(b * 1024 + qt * 64 + wave * 16) * 1024 + h * 64;
#pragma unroll
    for (int r = 0; r < 4; r++) {
        float inv = 1.f / l_run[r];
#pragma unroll
        for (int dt = 0; dt < 4; dt++)
            obase[(size_t)(quad * 4 + r) * 1024 + dt * 16 + l15] = f2bf(O[dt][r] * inv);
    }
}

// ---------------------------------------------------------------------------
// h = LayerNorm(h + r) * w + b ; writes fp32 h and bf16 hb.
// ---------------------------------------------------------------------------
__global__ __launch_bounds__(256) void ln_residual_kernel(
    float* __restrict__ h, unsigned short* __restrict__ hb,
    const float* __restrict__ r,
    const float* __restrict__ w, const float* __restrict__ b)
{
    const int row = blockIdx.x;
    const int tid = threadIdx.x;
    const int lane = tid & 63, wave = tid >> 6;

    float4 hv = *(float4*)&h[(size_t)row * 1024 + tid * 4];
    float4 rv = *(const float4*)&r[(size_t)row * 1024 + tid * 4];
    float x0 = hv.x + rv.x, x1 = hv.y + rv.y, x2 = hv.z + rv.z, x3 = hv.w + rv.w;

    float s  = x0 + x1 + x2 + x3;
    float s2 = x0 * x0 + x1 * x1 + x2 * x2 + x3 * x3;
#pragma unroll
    for (int off = 32; off >= 1; off >>= 1) {
        s  += __shfl_xor(s, off);
        s2 += __shfl_xor(s2, off);
    }
    __shared__ float ls[4], ls2[4];
    if (lane == 0) { ls[wave] = s; ls2[wave] = s2; }
    __syncthreads();
    s  = ls[0] + ls[1] + ls[2] + ls[3];
    s2 = ls2[0] + ls2[1] + ls2[2] + ls2[3];

    const float inv_n = 1.f / 1024.f;
    float mean = s * inv_n;
    float var  = s2 * inv_n - mean * mean;
    float rstd = rsqrtf(var + 1e-5f);

    float4 wv = *(const float4*)&w[tid * 4];
    float4 bv = *(const float4*)&b[tid * 4];
    float4 out;
    out.x = (x0 - mean) * rstd * wv.x + bv.x;
    out.y = (x1 - mean) * rstd * wv.y + bv.y;
    out.z = (x2 - mean) * rstd * wv.z + bv.z;
    out.w = (x3 - mean) * rstd * wv.w + bv.w;
    *(float4*)&h[(size_t)row * 1024 + tid * 4] = out;
    ushort4 ub;
    ub.x = f2bf(out.x); ub.y = f2bf(out.y); ub.z = f2bf(out.z); ub.w = f2bf(out.w);
    *(ushort4*)&hb[(size_t)row * 1024 + tid * 4] = ub;
}

__global__ __launch_bounds__(256) void copy_convert_kernel(
    const float* __restrict__ in, float* __restrict__ h, unsigned short* __restrict__ hb)
{
    int i = blockIdx.x * 256 + threadIdx.x;
    float4 v = ((const float4*)in)[i];
    ((float4*)h)[i] = v;
    ushort4 u;
    u.x = f2bf(v.x); u.y = f2bf(v.y); u.z = f2bf(v.z); u.w = f2bf(v.w);
    ((ushort4*)hb)[i] = u;
}

// ---------------------------------------------------------------------------
extern "C" void kernel_launch(void* const* d_in, const int* in_sizes, int n_in,
                              void* d_out, int out_size, void* d_ws, size_t ws_size,
                              hipStream_t stream)
{
    const float* x     = (const float*)d_in[0];
    const float* qkv_w = (const float*)d_in[1];
    const float* qkv_b = (const float*)d_in[2];
    const float* out_w = (const float*)d_in[3];
    const float* out_b = (const float*)d_in[4];
    const float* w1    = (const float*)d_in[5];
    const float* b1    = (const float*)d_in[6];
    const float* w2    = (const float*)d_in[7];
    const float* b2    = (const float*)d_in[8];
    const float* ln1w  = (const float*)d_in[9];
    const float* ln1b  = (const float*)d_in[10];
    const float* ln2w  = (const float*)d_in[11];
    const float* ln2b  = (const float*)d_in[12];

    float* h = (float*)d_out;                       // fp32 residual stream [4096,1024]
    char* ws = (char*)d_ws;
    // shared region: qkv bf16 [4096,3072] (25.2MB) aliased with t bf16 [4096,4096] (33.6MB)
    unsigned short* qkvb = (unsigned short*)ws;
    unsigned short* tb   = (unsigned short*)ws;
    unsigned short* ctxb = (unsigned short*)(ws + 33554432);          // [4096,1024] bf16
    unsigned short* hb   = (unsigned short*)(ws + 33554432 + 8388608); // [4096,1024] bf16
    unsigned short* wbf  = (unsigned short*)(ws + 50331648);          // 12.58M bf16 weights
    float*          r    = (float*)(ws + 75497472);                   // [4096,1024] fp32

    unsigned short* wb_qkv = wbf;
    unsigned short* wb_out = wbf + 3145728;
    unsigned short* wb_w1  = wbf + 4194304;
    unsigned short* wb_w2  = wbf + 8388608;

    copy_convert_kernel<<<4096, 256, 0, stream>>>(x, h, hb);

    for (int l = 0; l < 16; l++) {
        convert_weights_kernel<<<12288, 256, 0, stream>>>(
            qkv_w + (size_t)l * 3145728, out_w + (size_t)l * 1048576,
            w1 + (size_t)l * 4194304, w2 + (size_t)l * 4194304, wbf);

        // qkv = hb @ Wqkv^T + b           [4096,3072] bf16
        gemm_kernel<<<dim3(24, 32), 256, 0, stream>>>(
            hb, wb_qkv, qkv_b + (size_t)l * 3072, qkvb, 3072, 1024, 0, 1);
        // ctx = causal_attention(qkv)     [4096,1024] bf16
        attn_kernel<<<dim3(16, 64), 256, 0, stream>>>(qkvb, ctxb);
        // r = ctx @ Wout^T + b            fp32
        gemm_kernel<<<dim3(8, 32), 256, 0, stream>>>(
            ctxb, wb_out, out_b + (size_t)l * 1024, r, 1024, 1024, 0, 0);
        // h = LN1(h + r); hb = bf16(h)
        ln_residual_kernel<<<4096, 256, 0, stream>>>(
            h, hb, r, ln1w + (size_t)l * 1024, ln1b + (size_t)l * 1024);
        // t = relu(hb @ W1^T + b1)        [4096,4096] bf16
        gemm_kernel<<<dim3(32, 32), 256, 0, stream>>>(
            hb, wb_w1, b1 + (size_t)l * 4096, tb, 4096, 1024, 1, 1);
        // r = t @ W2^T + b2               fp32
        gemm_kernel<<<dim3(8, 32), 256, 0, stream>>>(
            tb, wb_w2, b2 + (size_t)l * 1024, r, 1024, 4096, 0, 0);
        // h = LN2(h + r); hb = bf16(h)
        ln_residual_kernel<<<4096, 256, 0, stream>>>(
            h, hb, r, ln2w + (size_t)l * 1024, ln2b + (size_t)l * 1024);
    }
}

// Round 2
// 5459.922 us; speedup vs baseline: 1.0986x; 1.0986x over previous
//
#include <hip/hip_runtime.h>
#include <hip/hip_bf16.h>

typedef float f32x4 __attribute__((ext_vector_type(4)));
typedef __bf16 bf16x8 __attribute__((ext_vector_type(8)));
typedef unsigned short ushort_t;

__device__ __forceinline__ unsigned short f2bf(float f) {
    unsigned int u = __builtin_bit_cast(unsigned int, f);
    u += 0x7fffu + ((u >> 16) & 1u);
    return (unsigned short)(u >> 16);
}

#define GCAST(p) ((const __attribute__((address_space(1))) void*)(p))
#define LCAST(p) ((__attribute__((address_space(3))) void*)(p))

// Swizzled LDS read of 8 bf16 from a [64][64] bf16 tile (128B rows).
__device__ __forceinline__ bf16x8 ldsw(const unsigned short* T, int row, int bcol) {
    return *reinterpret_cast<const bf16x8*>(
        reinterpret_cast<const char*>(T) + row * 128 + (bcol ^ ((row & 7) << 4)));
}

// T1: XCD-aware bijective block swizzle (nwg % 8 == 0 for all our grids).
// Consecutive output tiles land on the same XCD -> shared panels stay in its L2.
__device__ __forceinline__ int xcd_swizzle(int bid, int nwg) {
    int cpx = nwg >> 3;
    return (bid & 7) * cpx + (bid >> 3);
}

// ---------------------------------------------------------------------------
// Per-layer weight conversion: fp32 -> bf16 into wbf.
// ---------------------------------------------------------------------------
__global__ __launch_bounds__(256) void convert_weights_kernel(
    const float* __restrict__ qw, const float* __restrict__ ow,
    const float* __restrict__ w1, const float* __restrict__ w2,
    unsigned short* __restrict__ dst)
{
    int i = blockIdx.x * 256 + threadIdx.x;     // 0..3145727 (float4 idx)
    const float* src; int off;
    if (i < 786432)       { src = qw; off = i; }
    else if (i < 1048576) { src = ow; off = i - 786432; }
    else if (i < 2097152) { src = w1; off = i - 1048576; }
    else                  { src = w2; off = i - 2097152; }
    float4 v = ((const float4*)src)[off];
    ushort4 u;
    u.x = f2bf(v.x); u.y = f2bf(v.y); u.z = f2bf(v.z); u.w = f2bf(v.w);
    ((ushort4*)dst)[i] = u;
}

// ---------------------------------------------------------------------------
// GEMM: C[M,N] = A[M,K] @ W[N,K]^T + bias[N]; A,W bf16; C fp32 or bf16.
// 256 threads (4 waves), tile 128x128, BK=64, global_load_lds staging.
// ---------------------------------------------------------------------------
__global__ __launch_bounds__(256) void gemm_kernel(
    const unsigned short* __restrict__ A, const unsigned short* __restrict__ W,
    const float* __restrict__ bias, void* __restrict__ Cout,
    int N, int K, int relu, int out_bf16)
{
    __shared__ alignas(16) unsigned short As[128][64];
    __shared__ alignas(16) unsigned short Bs[128][64];

    const int tid  = threadIdx.x;
    const int nwg  = gridDim.x * gridDim.y;
    const int swz  = xcd_swizzle(blockIdx.y * gridDim.x + blockIdx.x, nwg);
    const int bn   = swz % gridDim.x, bm = swz / gridDim.x;
    const int wave = tid >> 6, lane = tid & 63;
    const int wm   = (wave >> 1) * 64, wn = (wave & 1) * 64;
    const int l15  = lane & 15, quad = lane >> 4;
    const int srow = lane >> 3;            // 0..7
    const int scol = (lane & 7) * 8;       // bf16 element col, 16B chunks

    f32x4 acc[4][4];
#pragma unroll
    for (int i = 0; i < 4; i++)
#pragma unroll
        for (int j = 0; j < 4; j++) acc[i][j] = f32x4{0.f, 0.f, 0.f, 0.f};

    const unsigned short* Abase = A + (size_t)(bm * 128) * K;
    const unsigned short* Wbase = W + (size_t)(bn * 128) * K;

    for (int k0 = 0; k0 < K; k0 += 64) {
        __syncthreads();
#pragma unroll
        for (int i = 0; i < 4; i++) {
            int r0 = (i * 4 + wave) * 8;   // wave-uniform base row
            __builtin_amdgcn_global_load_lds(
                GCAST(&Abase[(size_t)(r0 + srow) * K + k0 + scol]),
                LCAST(&As[r0][0]), 16, 0, 0);
            __builtin_amdgcn_global_load_lds(
                GCAST(&Wbase[(size_t)(r0 + srow) * K + k0 + scol]),
                LCAST(&Bs[r0][0]), 16, 0, 0);
        }
        __syncthreads();

#pragma unroll
        for (int ks = 0; ks < 2; ks++) {
            bf16x8 a[4], b[4];
#pragma unroll
            for (int mt = 0; mt < 4; mt++)
                a[mt] = *reinterpret_cast<const bf16x8*>(&As[wm + mt * 16 + l15][ks * 32 + quad * 8]);
#pragma unroll
            for (int nt = 0; nt < 4; nt++)
                b[nt] = *reinterpret_cast<const bf16x8*>(&Bs[wn + nt * 16 + l15][ks * 32 + quad * 8]);
#pragma unroll
            for (int mt = 0; mt < 4; mt++)
#pragma unroll
                for (int nt = 0; nt < 4; nt++)
                    acc[mt][nt] = __builtin_amdgcn_mfma_f32_16x16x32_bf16(
                        a[mt], b[nt], acc[mt][nt], 0, 0, 0);
        }
    }

    float* Cf = (float*)Cout;
    unsigned short* Cb = (unsigned short*)Cout;
#pragma unroll
    for (int nt = 0; nt < 4; nt++) {
        int gn = bn * 128 + wn + nt * 16 + l15;
        float bv = bias[gn];
#pragma unroll
        for (int mt = 0; mt < 4; mt++) {
            int gm0 = bm * 128 + wm + mt * 16 + quad * 4;
#pragma unroll
            for (int r = 0; r < 4; r++) {
                float v = acc[mt][nt][r] + bv;
                if (relu) v = fmaxf(v, 0.f);
                if (out_bf16) Cb[(size_t)(gm0 + r) * N + gn] = f2bf(v);
                else          Cf[(size_t)(gm0 + r) * N + gn] = v;
            }
        }
    }
}

// ---------------------------------------------------------------------------
// Split-K GEMM (fp32 out, no relu): blockIdx.z selects K-half and output
// buffer. C0 gets bias, C1 doesn't; the LN kernel sums h + C0 + C1.
// Doubles blocks/CU for the N=1024 GEMMs (1 -> 2) so wave-level overlap
// (m114) can hide the global_load_lds drain.
// ---------------------------------------------------------------------------
__global__ __launch_bounds__(256) void gemm_splitk_kernel(
    const unsigned short* __restrict__ A, const unsigned short* __restrict__ W,
    const float* __restrict__ bias, float* __restrict__ C0, float* __restrict__ C1,
    int N, int K)
{
    __shared__ alignas(16) unsigned short As[128][64];
    __shared__ alignas(16) unsigned short Bs[128][64];

    const int tid  = threadIdx.x;
    const int nwg  = gridDim.x * gridDim.y;
    const int swz  = xcd_swizzle(blockIdx.y * gridDim.x + blockIdx.x, nwg);
    const int bn   = swz % gridDim.x, bm = swz / gridDim.x;
    const int kz   = blockIdx.z;               // 0 or 1
    const int kbeg = kz * (K >> 1);
    const int kend = kbeg + (K >> 1);
    const int wave = tid >> 6, lane = tid & 63;
    const int wm   = (wave >> 1) * 64, wn = (wave & 1) * 64;
    const int l15  = lane & 15, quad = lane >> 4;
    const int srow = lane >> 3;
    const int scol = (lane & 7) * 8;

    f32x4 acc[4][4];
#pragma unroll
    for (int i = 0; i < 4; i++)
#pragma unroll
        for (int j = 0; j < 4; j++) acc[i][j] = f32x4{0.f, 0.f, 0.f, 0.f};

    const unsigned short* Abase = A + (size_t)(bm * 128) * K;
    const unsigned short* Wbase = W + (size_t)(bn * 128) * K;

    for (int k0 = kbeg; k0 < kend; k0 += 64) {
        __syncthreads();
#pragma unroll
        for (int i = 0; i < 4; i++) {
            int r0 = (i * 4 + wave) * 8;
            __builtin_amdgcn_global_load_lds(
                GCAST(&Abase[(size_t)(r0 + srow) * K + k0 + scol]),
                LCAST(&As[r0][0]), 16, 0, 0);
            __builtin_amdgcn_global_load_lds(
                GCAST(&Wbase[(size_t)(r0 + srow) * K + k0 + scol]),
                LCAST(&Bs[r0][0]), 16, 0, 0);
        }
        __syncthreads();

#pragma unroll
        for (int ks = 0; ks < 2; ks++) {
            bf16x8 a[4], b[4];
#pragma unroll
            for (int mt = 0; mt < 4; mt++)
                a[mt] = *reinterpret_cast<const bf16x8*>(&As[wm + mt * 16 + l15][ks * 32 + quad * 8]);
#pragma unroll
            for (int nt = 0; nt < 4; nt++)
                b[nt] = *reinterpret_cast<const bf16x8*>(&Bs[wn + nt * 16 + l15][ks * 32 + quad * 8]);
#pragma unroll
            for (int mt = 0; mt < 4; mt++)
#pragma unroll
                for (int nt = 0; nt < 4; nt++)
                    acc[mt][nt] = __builtin_amdgcn_mfma_f32_16x16x32_bf16(
                        a[mt], b[nt], acc[mt][nt], 0, 0, 0);
        }
    }

    float* Cf = kz ? C1 : C0;
#pragma unroll
    for (int nt = 0; nt < 4; nt++) {
        int gn = bn * 128 + wn + nt * 16 + l15;
        float bv = kz ? 0.f : bias[gn];
#pragma unroll
        for (int mt = 0; mt < 4; mt++) {
            int gm0 = bm * 128 + wm + mt * 16 + quad * 4;
#pragma unroll
            for (int r = 0; r < 4; r++)
                Cf[(size_t)(gm0 + r) * N + gn] = acc[mt][nt][r] + bv;
        }
    }
}

// ---------------------------------------------------------------------------
// Flash attention, causal. One block = (b, h, 64-row q tile). 256 threads.
// ---------------------------------------------------------------------------
__global__ __launch_bounds__(256) void attn_kernel(
    const unsigned short* __restrict__ qkv, unsigned short* __restrict__ ctx)
{
    const int qt = blockIdx.x;          // 0..15
    const int bh = blockIdx.y;          // 0..63
    const int b  = bh >> 4, h = bh & 15;
    const int tid = threadIdx.x, wave = tid >> 6, lane = tid & 63;
    const int l15 = lane & 15, quad = lane >> 4;
    const int srow = lane >> 3;
    const int scolz = ((lane & 7) ^ srow) * 8;   // pre-swizzled global source col
    const float scale = 0.125f;         // 1/sqrt(64)

    __shared__ alignas(16) unsigned short Qs[64][64];
    __shared__ alignas(16) unsigned short Ks[64][64];
    __shared__ alignas(16) unsigned short Vt[64][64];  // [d][k], swizzled
    __shared__ alignas(16) unsigned short Ps[64][64];

    const unsigned short* qbase = qkv + (size_t)(b * 1024 + qt * 64) * 3072 + h * 64;
#pragma unroll
    for (int i = 0; i < 2; i++) {
        int r0 = (i * 4 + wave) * 8;
        __builtin_amdgcn_global_load_lds(
            GCAST(&qbase[(size_t)(r0 + srow) * 3072 + scolz]),
            LCAST(&Qs[r0][0]), 16, 0, 0);
    }

    f32x4 O[4];
#pragma unroll
    for (int dt = 0; dt < 4; dt++) O[dt] = f32x4{0.f, 0.f, 0.f, 0.f};
    float m_run[4], l_run[4];
#pragma unroll
    for (int r = 0; r < 4; r++) { m_run[r] = -__builtin_inff(); l_run[r] = 0.f; }

    const int q_row_base = qt * 64 + wave * 16;

    for (int j = 0; j <= qt; j++) {
        __syncthreads();
        const unsigned short* kbase = qkv + (size_t)(b * 1024 + j * 64) * 3072 + 1024 + h * 64;
        const unsigned short* vbase = qkv + (size_t)(b * 1024 + j * 64) * 3072 + 2048 + h * 64;
#pragma unroll
        for (int i = 0; i < 2; i++) {
            int r0 = (i * 4 + wave) * 8;
            __builtin_amdgcn_global_load_lds(
                GCAST(&kbase[(size_t)(r0 + srow) * 3072 + scolz]),
                LCAST(&Ks[r0][0]), 16, 0, 0);
        }
#pragma unroll
        for (int i = 0; i < 4; i++) {
            int idx = tid + i * 256;
            int k = idx >> 4, c4 = (idx & 15) * 4;
            ushort4 vv = *(const ushort4*)&vbase[(size_t)k * 3072 + c4];
            char* vt = (char*)Vt;
            int klo = (k & 7) * 2;          // byte offset within 16B chunk
            int kch = (k >> 3) << 4;        // chunk byte base
            const unsigned short* vp = (const unsigned short*)&vv;
#pragma unroll
            for (int j2 = 0; j2 < 4; j2++) {
                int d = c4 + j2;
                *(unsigned short*)(vt + d * 128 + ((kch ^ ((d & 7) << 4)) | klo)) = vp[j2];
            }
        }
        __syncthreads();

        // S = Q K^T
        f32x4 Sc[4];
#pragma unroll
        for (int nt = 0; nt < 4; nt++) Sc[nt] = f32x4{0.f, 0.f, 0.f, 0.f};
        __builtin_amdgcn_s_setprio(1);
#pragma unroll
        for (int ks = 0; ks < 2; ks++) {
            bf16x8 aq = ldsw(&Qs[0][0], wave * 16 + l15, ks * 64 + quad * 16);
#pragma unroll
            for (int nt = 0; nt < 4; nt++) {
                bf16x8 bk = ldsw(&Ks[0][0], nt * 16 + l15, ks * 64 + quad * 16);
                Sc[nt] = __builtin_amdgcn_mfma_f32_16x16x32_bf16(aq, bk, Sc[nt], 0, 0, 0);
            }
        }
        __builtin_amdgcn_s_setprio(0);

#pragma unroll
        for (int nt = 0; nt < 4; nt++)
#pragma unroll
            for (int r = 0; r < 4; r++) Sc[nt][r] *= scale;

        if (j == qt) {   // causal mask only touches the diagonal tile
#pragma unroll
            for (int r = 0; r < 4; r++) {
                int qg = q_row_base + quad * 4 + r;
#pragma unroll
                for (int nt = 0; nt < 4; nt++) {
                    int kg = j * 64 + nt * 16 + l15;
                    if (kg > qg) Sc[nt][r] = -__builtin_inff();
                }
            }
        }

        float alpha[4];
#pragma unroll
        for (int r = 0; r < 4; r++) {
            float mx = -__builtin_inff();
#pragma unroll
            for (int nt = 0; nt < 4; nt++) mx = fmaxf(mx, Sc[nt][r]);
#pragma unroll
            for (int off = 1; off < 16; off <<= 1) mx = fmaxf(mx, __shfl_xor(mx, off));
            float mnew = fmaxf(m_run[r], mx);
            alpha[r] = __expf(m_run[r] - mnew);
            m_run[r] = mnew;
        }

#pragma unroll
        for (int r = 0; r < 4; r++) {
            float sum = 0.f;
#pragma unroll
            for (int nt = 0; nt < 4; nt++) {
                float p = __expf(Sc[nt][r] - m_run[r]);
                Sc[nt][r] = p;
                sum += p;
            }
#pragma unroll
            for (int off = 1; off < 16; off <<= 1) sum += __shfl_xor(sum, off);
            l_run[r] = l_run[r] * alpha[r] + sum;
        }

#pragma unroll
        for (int dt = 0; dt < 4; dt++)
#pragma unroll
            for (int r = 0; r < 4; r++) O[dt][r] *= alpha[r];

        {
            char* ps = (char*)Ps;
#pragma unroll
            for (int nt = 0; nt < 4; nt++)
#pragma unroll
                for (int r = 0; r < 4; r++) {
                    int row = wave * 16 + quad * 4 + r;
                    int col = nt * 16 + l15;
                    *(unsigned short*)(ps + row * 128 + ((col * 2) ^ ((row & 7) << 4)))
                        = f2bf(Sc[nt][r]);
                }
        }

        __builtin_amdgcn_s_setprio(1);
#pragma unroll
        for (int ks = 0; ks < 2; ks++) {
            bf16x8 ap = ldsw(&Ps[0][0], wave * 16 + l15, ks * 64 + quad * 16);
#pragma unroll
            for (int dt = 0; dt < 4; dt++) {
                bf16x8 bv = ldsw(&Vt[0][0], dt * 16 + l15, ks * 64 + quad * 16);
                O[dt] = __builtin_amdgcn_mfma_f32_16x16x32_bf16(ap, bv, O[dt], 0, 0, 0);
            }
        }
        __builtin_amdgcn_s_setprio(0);
    }

    unsigned short* obase = ctx + (size_t)(b * 1024 + qt * 64 + wave * 16) * 1024 + h * 64;
#pragma unroll
    for (int r = 0; r < 4; r++) {
        float inv = 1.f / l_run[r];
#pragma unroll
        for (int dt = 0; dt < 4; dt++)
            obase[(size_t)(quad * 4 + r) * 1024 + dt * 16 + l15] = f2bf(O[dt][r] * inv);
    }
}

// ---------------------------------------------------------------------------
// h = LayerNorm(h + r + r2) * w + b ; writes fp32 h and bf16 hb.
// ---------------------------------------------------------------------------
__global__ __launch_bounds__(256) void ln_residual_kernel(
    float* __restrict__ h, unsigned short* __restrict__ hb,
    const float* __restrict__ r, const float* __restrict__ r2,
    const float* __restrict__ w, const float* __restrict__ b)
{
    const int row = blockIdx.x;
    const int tid = threadIdx.x;
    const int lane = tid & 63, wave = tid >> 6;

    float4 hv = *(float4*)&h[(size_t)row * 1024 + tid * 4];
    float4 rv = *(const float4*)&r[(size_t)row * 1024 + tid * 4];
    float4 r2v = *(const float4*)&r2[(size_t)row * 1024 + tid * 4];
    float x0 = hv.x + rv.x + r2v.x, x1 = hv.y + rv.y + r2v.y;
    float x2 = hv.z + rv.z + r2v.z, x3 = hv.w + rv.w + r2v.w;

    float s  = x0 + x1 + x2 + x3;
    float s2 = x0 * x0 + x1 * x1 + x2 * x2 + x3 * x3;
#pragma unroll
    for (int off = 32; off >= 1; off >>= 1) {
        s  += __shfl_xor(s, off);
        s2 += __shfl_xor(s2, off);
    }
    __shared__ float ls[4], ls2[4];
    if (lane == 0) { ls[wave] = s; ls2[wave] = s2; }
    __syncthreads();
    s  = ls[0] + ls[1] + ls[2] + ls[3];
    s2 = ls2[0] + ls2[1] + ls2[2] + ls2[3];

    const float inv_n = 1.f / 1024.f;
    float mean = s * inv_n;
    float var  = s2 * inv_n - mean * mean;
    float rstd = rsqrtf(var + 1e-5f);

    float4 wv = *(const float4*)&w[tid * 4];
    float4 bv = *(const float4*)&b[tid * 4];
    float4 out;
    out.x = (x0 - mean) * rstd * wv.x + bv.x;
    out.y = (x1 - mean) * rstd * wv.y + bv.y;
    out.z = (x2 - mean) * rstd * wv.z + bv.z;
    out.w = (x3 - mean) * rstd * wv.w + bv.w;
    *(float4*)&h[(size_t)row * 1024 + tid * 4] = out;
    ushort4 ub;
    ub.x = f2bf(out.x); ub.y = f2bf(out.y); ub.z = f2bf(out.z); ub.w = f2bf(out.w);
    *(ushort4*)&hb[(size_t)row * 1024 + tid * 4] = ub;
}

__global__ __launch_bounds__(256) void copy_convert_kernel(
    const float* __restrict__ in, float* __restrict__ h, unsigned short* __restrict__ hb)
{
    int i = blockIdx.x * 256 + threadIdx.x;
    float4 v = ((const float4*)in)[i];
    ((float4*)h)[i] = v;
    ushort4 u;
    u.x = f2bf(v.x); u.y = f2bf(v.y); u.z = f2bf(v.z); u.w = f2bf(v.w);
    ((ushort4*)hb)[i] = u;
}

// ---------------------------------------------------------------------------
extern "C" void kernel_launch(void* const* d_in, const int* in_sizes, int n_in,
                              void* d_out, int out_size, void* d_ws, size_t ws_size,
                              hipStream_t stream)
{
    const float* x     = (const float*)d_in[0];
    const float* qkv_w = (const float*)d_in[1];
    const float* qkv_b = (const float*)d_in[2];
    const float* out_w = (const float*)d_in[3];
    const float* out_b = (const float*)d_in[4];
    const float* w1    = (const float*)d_in[5];
    const float* b1    = (const float*)d_in[6];
    const float* w2    = (const float*)d_in[7];
    const float* b2    = (const float*)d_in[8];
    const float* ln1w  = (const float*)d_in[9];
    const float* ln1b  = (const float*)d_in[10];
    const float* ln2w  = (const float*)d_in[11];
    const float* ln2b  = (const float*)d_in[12];

    float* h = (float*)d_out;                       // fp32 residual stream [4096,1024]
    char* ws = (char*)d_ws;
    // layout: qkv bf16 [4096,3072] aliased with t bf16 [4096,4096]
    unsigned short* qkvb = (unsigned short*)ws;
    unsigned short* tb   = (unsigned short*)ws;
    unsigned short* ctxb = (unsigned short*)(ws + 33554432);           // [4096,1024] bf16
    unsigned short* hb   = (unsigned short*)(ws + 33554432 + 8388608); // [4096,1024] bf16
    unsigned short* wbf  = (unsigned short*)(ws + 50331648);           // 12.58M bf16 weights
    float*          r    = (float*)(ws + 75497472);                    // [4096,1024] fp32
    float*          r2   = (float*)(ws + 92274688);                    // [4096,1024] fp32

    unsigned short* wb_qkv = wbf;
    unsigned short* wb_out = wbf + 3145728;
    unsigned short* wb_w1  = wbf + 4194304;
    unsigned short* wb_w2  = wbf + 8388608;

    copy_convert_kernel<<<4096, 256, 0, stream>>>(x, h, hb);

    for (int l = 0; l < 16; l++) {
        convert_weights_kernel<<<12288, 256, 0, stream>>>(
            qkv_w + (size_t)l * 3145728, out_w + (size_t)l * 1048576,
            w1 + (size_t)l * 4194304, w2 + (size_t)l * 4194304, wbf);

        // qkv = hb @ Wqkv^T + b           [4096,3072] bf16
        gemm_kernel<<<dim3(24, 32), 256, 0, stream>>>(
            hb, wb_qkv, qkv_b + (size_t)l * 3072, qkvb, 3072, 1024, 0, 1);
        // ctx = causal_attention(qkv)     [4096,1024] bf16
        attn_kernel<<<dim3(16, 64), 256, 0, stream>>>(qkvb, ctxb);
        // r + r2 = ctx @ Wout^T + b       fp32 partials (split-K=2)
        gemm_splitk_kernel<<<dim3(8, 32, 2), 256, 0, stream>>>(
            ctxb, wb_out, out_b + (size_t)l * 1024, r, r2, 1024, 1024);
        // h = LN1(h + r + r2); hb = bf16(h)
        ln_residual_kernel<<<4096, 256, 0, stream>>>(
            h, hb, r, r2, ln1w + (size_t)l * 1024, ln1b + (size_t)l * 1024);
        // t = relu(hb @ W1^T + b1)        [4096,4096] bf16
        gemm_kernel<<<dim3(32, 32), 256, 0, stream>>>(
            hb, wb_w1, b1 + (size_t)l * 4096, tb, 4096, 1024, 1, 1);
        // r + r2 = t @ W2^T + b2          fp32 partials (split-K=2)
        gemm_splitk_kernel<<<dim3(8, 32, 2), 256, 0, stream>>>(
            tb, wb_w2, b2 + (size_t)l * 1024, r, r2, 1024, 4096);
        // h = LN2(h + r + r2); hb = bf16(h)
        ln_residual_kernel<<<4096, 256, 0, stream>>>(
            h, hb, r, r2, ln2w + (size_t)l * 1024, ln2b + (size_t)l * 1024);
    }
}

// Round 3
// 4980.502 us; speedup vs baseline: 1.2043x; 1.0963x over previous
//
#include <hip/hip_runtime.h>
#include <hip/hip_bf16.h>

typedef float f32x4 __attribute__((ext_vector_type(4)));
typedef __bf16 bf16x8 __attribute__((ext_vector_type(8)));
typedef unsigned short ushort_t;

__device__ __forceinline__ unsigned short f2bf(float f) {
    unsigned int u = __builtin_bit_cast(unsigned int, f);
    u += 0x7fffu + ((u >> 16) & 1u);
    return (unsigned short)(u >> 16);
}

#define GCAST(p) ((const __attribute__((address_space(1))) void*)(p))
#define LCAST(p) ((__attribute__((address_space(3))) void*)(p))

// Swizzled LDS read of 8 bf16 from a tile with 128B rows.
__device__ __forceinline__ bf16x8 ldsw(const unsigned short* T, int row, int bcol) {
    return *reinterpret_cast<const bf16x8*>(
        reinterpret_cast<const char*>(T) + row * 128 + (bcol ^ ((row & 7) << 4)));
}

// T1: XCD-aware bijective block swizzle (all grids have nwg % 8 == 0).
__device__ __forceinline__ int xcd_swizzle(int bid, int nwg) {
    int cpx = nwg >> 3;
    return (bid & 7) * cpx + (bid >> 3);
}

// ---------------------------------------------------------------------------
// Per-layer weight conversion: fp32 -> bf16 into wbf.
// ---------------------------------------------------------------------------
__global__ __launch_bounds__(256) void convert_weights_kernel(
    const float* __restrict__ qw, const float* __restrict__ ow,
    const float* __restrict__ w1, const float* __restrict__ w2,
    unsigned short* __restrict__ dst)
{
    int i = blockIdx.x * 256 + threadIdx.x;     // 0..3145727 (float4 idx)
    const float* src; int off;
    if (i < 786432)       { src = qw; off = i; }
    else if (i < 1048576) { src = ow; off = i - 786432; }
    else if (i < 2097152) { src = w1; off = i - 1048576; }
    else                  { src = w2; off = i - 2097152; }
    float4 v = ((const float4*)src)[off];
    ushort4 u;
    u.x = f2bf(v.x); u.y = f2bf(v.y); u.z = f2bf(v.z); u.w = f2bf(v.w);
    ((ushort4*)dst)[i] = u;
}

// ---------------------------------------------------------------------------
// 256x256-tile GEMM with counted-vmcnt prefetch pipeline (T2+T3/T4+T5).
// C[M,N] = A[M,K] @ W[N,K]^T + bias[N], bf16 out, optional relu.
// 512 threads = 8 waves (2M x 4N), BK=64, LDS 128 KiB (2 tile buffers).
// Schedule per K-tile t (buf = t&1):
//   ph0..ph3: quadrant MFMAs (16 each) with per-phase ds_reads (12/4/8/0)
//   barrier#1  (all waves' reads of buf done: last read completes at ph2's
//              lgkmcnt(0), ph3 is register-only)
//   stage tile t+2 -> buf (8 global_load_lds)   [skipped near the end]
//   s_waitcnt vmcnt(8)  (waits tile t+1's loads; t+2's stay IN FLIGHT
//                        across the barrier -- never drains fresh loads)
//   barrier#2
// LDS is T2-swizzled: linear gload_lds dest + pre-swizzled global source,
// reads XOR the same (row&7)<<4 (both-sides rule #21; same pattern as attn).
// ---------------------------------------------------------------------------
__global__ __launch_bounds__(512, 2) void gemm256_kernel(
    const unsigned short* __restrict__ A, const unsigned short* __restrict__ W,
    const float* __restrict__ bias, unsigned short* __restrict__ C,
    int N, int K, int relu)
{
    __shared__ alignas(16) unsigned short As[2][256][64];   // 64 KB
    __shared__ alignas(16) unsigned short Bs[2][256][64];   // 64 KB

    const int tid  = threadIdx.x;
    const int wave = tid >> 6, lane = tid & 63;
    const int nwg  = gridDim.x * gridDim.y;
    const int swz  = xcd_swizzle(blockIdx.y * gridDim.x + blockIdx.x, nwg);
    const int bn   = swz % gridDim.x, bm = swz / gridDim.x;
    const int wr   = wave >> 2;            // 0..1  (M)
    const int wc   = wave & 3;             // 0..3  (N)
    const int l15  = lane & 15, quad = lane >> 4;
    const int srow8  = lane >> 3;
    const int schunk = ((lane & 7) ^ srow8) * 8;  // pre-swizzled source chunk

    const unsigned short* Abase = A + (size_t)(bm * 256) * K;
    const unsigned short* Wbase = W + (size_t)(bn * 256) * K;

    f32x4 acc[8][4];
#pragma unroll
    for (int i = 0; i < 8; i++)
#pragma unroll
        for (int j = 0; j < 4; j++) acc[i][j] = f32x4{0.f, 0.f, 0.f, 0.f};

    const int NT = K >> 6;   // K-tiles of 64

    // Stage one K-tile (A+B, 8 gload_lds/thread). Wave-uniform LDS base;
    // HW adds lane*16 -> rows s*64 + wave*8 + (lane>>3), chunk lane&7.
#define STAGE256(buf_, t_) do {                                               \
    int k0_ = (t_) * 64;                                                      \
    _Pragma("unroll")                                                         \
    for (int s = 0; s < 4; s++) {                                             \
        __builtin_amdgcn_global_load_lds(                                     \
            GCAST(&Abase[(size_t)(s * 64 + wave * 8 + srow8) * K + k0_ + schunk]), \
            LCAST(&As[buf_][s * 64 + wave * 8][0]), 16, 0, 0);                \
        __builtin_amdgcn_global_load_lds(                                     \
            GCAST(&Wbase[(size_t)(s * 64 + wave * 8 + srow8) * K + k0_ + schunk]), \
            LCAST(&Bs[buf_][s * 64 + wave * 8][0]), 16, 0, 0);                \
    }                                                                         \
} while (0)

    // Prologue: tiles 0,1 staged; wait tile 0 only (8 newest stay in flight).
    STAGE256(0, 0);
    STAGE256(1, 1);
    asm volatile("s_waitcnt vmcnt(8)" ::: "memory");
    __builtin_amdgcn_s_barrier();

    for (int t = 0; t < NT; t++) {
        const unsigned short* Al = &As[t & 1][0][0];
        const unsigned short* Bl = &Bs[t & 1][0][0];
        bf16x8 aA[4][2], bB0[2][2], bB1[2][2];

        // ---- ph0: read A(mh=0) 8 + B(nh=0) 4; MFMA quadrant (0,0)
#pragma unroll
        for (int mt = 0; mt < 4; mt++)
#pragma unroll
            for (int ks = 0; ks < 2; ks++)
                aA[mt][ks] = ldsw(Al, wr * 128 + mt * 16 + l15, ks * 64 + quad * 16);
#pragma unroll
        for (int nt = 0; nt < 2; nt++)
#pragma unroll
            for (int ks = 0; ks < 2; ks++)
                bB0[nt][ks] = ldsw(Bl, wc * 64 + nt * 16 + l15, ks * 64 + quad * 16);
        asm volatile("s_waitcnt lgkmcnt(0)" ::: "memory");
        __builtin_amdgcn_sched_barrier(0);
        __builtin_amdgcn_s_setprio(1);
#pragma unroll
        for (int mt = 0; mt < 4; mt++)
#pragma unroll
            for (int nt = 0; nt < 2; nt++)
#pragma unroll
                for (int ks = 0; ks < 2; ks++)
                    acc[mt][nt] = __builtin_amdgcn_mfma_f32_16x16x32_bf16(
                        aA[mt][ks], bB0[nt][ks], acc[mt][nt], 0, 0, 0);
        __builtin_amdgcn_s_setprio(0);

        // ---- ph1: read B(nh=1) 4; MFMA quadrant (0,1)
#pragma unroll
        for (int nt = 0; nt < 2; nt++)
#pragma unroll
            for (int ks = 0; ks < 2; ks++)
                bB1[nt][ks] = ldsw(Bl, wc * 64 + (nt + 2) * 16 + l15, ks * 64 + quad * 16);
        asm volatile("s_waitcnt lgkmcnt(0)" ::: "memory");
        __builtin_amdgcn_sched_barrier(0);
        __builtin_amdgcn_s_setprio(1);
#pragma unroll
        for (int mt = 0; mt < 4; mt++)
#pragma unroll
            for (int nt = 0; nt < 2; nt++)
#pragma unroll
                for (int ks = 0; ks < 2; ks++)
                    acc[mt][nt + 2] = __builtin_amdgcn_mfma_f32_16x16x32_bf16(
                        aA[mt][ks], bB1[nt][ks], acc[mt][nt + 2], 0, 0, 0);
        __builtin_amdgcn_s_setprio(0);

        // ---- ph2: read A(mh=1) 8; MFMA quadrant (1,1)
#pragma unroll
        for (int mt = 0; mt < 4; mt++)
#pragma unroll
            for (int ks = 0; ks < 2; ks++)
                aA[mt][ks] = ldsw(Al, wr * 128 + (mt + 4) * 16 + l15, ks * 64 + quad * 16);
        asm volatile("s_waitcnt lgkmcnt(0)" ::: "memory");
        __builtin_amdgcn_sched_barrier(0);
        __builtin_amdgcn_s_setprio(1);
#pragma unroll
        for (int mt = 0; mt < 4; mt++)
#pragma unroll
            for (int nt = 0; nt < 2; nt++)
#pragma unroll
                for (int ks = 0; ks < 2; ks++)
                    acc[mt + 4][nt + 2] = __builtin_amdgcn_mfma_f32_16x16x32_bf16(
                        aA[mt][ks], bB1[nt][ks], acc[mt + 4][nt + 2], 0, 0, 0);
        __builtin_amdgcn_s_setprio(0);

        // ---- ph3: register-only; MFMA quadrant (1,0)
        __builtin_amdgcn_s_setprio(1);
#pragma unroll
        for (int mt = 0; mt < 4; mt++)
#pragma unroll
            for (int nt = 0; nt < 2; nt++)
#pragma unroll
                for (int ks = 0; ks < 2; ks++)
                    acc[mt + 4][nt] = __builtin_amdgcn_mfma_f32_16x16x32_bf16(
                        aA[mt][ks], bB0[nt][ks], acc[mt + 4][nt], 0, 0, 0);
        __builtin_amdgcn_s_setprio(0);

        // ---- group boundary: stage t+2 into this buffer AFTER all reads done
        __builtin_amdgcn_s_barrier();                 // #1
        if (t + 2 < NT) {
            STAGE256(t & 1, t + 2);
            asm volatile("s_waitcnt vmcnt(8)" ::: "memory");  // waits tile t+1
        } else {
            asm volatile("s_waitcnt vmcnt(0)" ::: "memory");  // old loads only
        }
        __builtin_amdgcn_s_barrier();                 // #2
    }
#undef STAGE256

    // Epilogue: bf16 out, bias + optional relu.
#pragma unroll
    for (int nt = 0; nt < 4; nt++) {
        int gn = bn * 256 + wc * 64 + nt * 16 + l15;
        float bv = bias[gn];
#pragma unroll
        for (int mt = 0; mt < 8; mt++) {
            int gm0 = bm * 256 + wr * 128 + mt * 16 + quad * 4;
#pragma unroll
            for (int r = 0; r < 4; r++) {
                float v = acc[mt][nt][r] + bv;
                if (relu) v = fmaxf(v, 0.f);
                C[(size_t)(gm0 + r) * N + gn] = f2bf(v);
            }
        }
    }
}

// ---------------------------------------------------------------------------
// Split-K GEMM (fp32 out, no relu), 128x128 tile: blockIdx.z selects K-half
// and output buffer. C0 gets bias; LN sums h + C0 + C1.
// ---------------------------------------------------------------------------
__global__ __launch_bounds__(256) void gemm_splitk_kernel(
    const unsigned short* __restrict__ A, const unsigned short* __restrict__ W,
    const float* __restrict__ bias, float* __restrict__ C0, float* __restrict__ C1,
    int N, int K)
{
    __shared__ alignas(16) unsigned short As[128][64];
    __shared__ alignas(16) unsigned short Bs[128][64];

    const int tid  = threadIdx.x;
    const int nwg  = gridDim.x * gridDim.y;
    const int swz  = xcd_swizzle(blockIdx.y * gridDim.x + blockIdx.x, nwg);
    const int bn   = swz % gridDim.x, bm = swz / gridDim.x;
    const int kz   = blockIdx.z;               // 0 or 1
    const int kbeg = kz * (K >> 1);
    const int kend = kbeg + (K >> 1);
    const int wave = tid >> 6, lane = tid & 63;
    const int wm   = (wave >> 1) * 64, wn = (wave & 1) * 64;
    const int l15  = lane & 15, quad = lane >> 4;
    const int srow = lane >> 3;
    const int scol = (lane & 7) * 8;

    f32x4 acc[4][4];
#pragma unroll
    for (int i = 0; i < 4; i++)
#pragma unroll
        for (int j = 0; j < 4; j++) acc[i][j] = f32x4{0.f, 0.f, 0.f, 0.f};

    const unsigned short* Abase = A + (size_t)(bm * 128) * K;
    const unsigned short* Wbase = W + (size_t)(bn * 128) * K;

    for (int k0 = kbeg; k0 < kend; k0 += 64) {
        __syncthreads();
#pragma unroll
        for (int i = 0; i < 4; i++) {
            int r0 = (i * 4 + wave) * 8;
            __builtin_amdgcn_global_load_lds(
                GCAST(&Abase[(size_t)(r0 + srow) * K + k0 + scol]),
                LCAST(&As[r0][0]), 16, 0, 0);
            __builtin_amdgcn_global_load_lds(
                GCAST(&Wbase[(size_t)(r0 + srow) * K + k0 + scol]),
                LCAST(&Bs[r0][0]), 16, 0, 0);
        }
        __syncthreads();

#pragma unroll
        for (int ks = 0; ks < 2; ks++) {
            bf16x8 a[4], b[4];
#pragma unroll
            for (int mt = 0; mt < 4; mt++)
                a[mt] = *reinterpret_cast<const bf16x8*>(&As[wm + mt * 16 + l15][ks * 32 + quad * 8]);
#pragma unroll
            for (int nt = 0; nt < 4; nt++)
                b[nt] = *reinterpret_cast<const bf16x8*>(&Bs[wn + nt * 16 + l15][ks * 32 + quad * 8]);
#pragma unroll
            for (int mt = 0; mt < 4; mt++)
#pragma unroll
                for (int nt = 0; nt < 4; nt++)
                    acc[mt][nt] = __builtin_amdgcn_mfma_f32_16x16x32_bf16(
                        a[mt], b[nt], acc[mt][nt], 0, 0, 0);
        }
    }

    float* Cf = kz ? C1 : C0;
#pragma unroll
    for (int nt = 0; nt < 4; nt++) {
        int gn = bn * 128 + wn + nt * 16 + l15;
        float bv = kz ? 0.f : bias[gn];
#pragma unroll
        for (int mt = 0; mt < 4; mt++) {
            int gm0 = bm * 128 + wm + mt * 16 + quad * 4;
#pragma unroll
            for (int r = 0; r < 4; r++)
                Cf[(size_t)(gm0 + r) * N + gn] = acc[mt][nt][r] + bv;
        }
    }
}

// ---------------------------------------------------------------------------
// Flash attention, causal. One block = (b, h, 64-row q tile). 256 threads.
// ---------------------------------------------------------------------------
__global__ __launch_bounds__(256) void attn_kernel(
    const unsigned short* __restrict__ qkv, unsigned short* __restrict__ ctx)
{
    const int qt = blockIdx.x;          // 0..15
    const int bh = blockIdx.y;          // 0..63
    const int b  = bh >> 4, h = bh & 15;
    const int tid = threadIdx.x, wave = tid >> 6, lane = tid & 63;
    const int l15 = lane & 15, quad = lane >> 4;
    const int srow = lane >> 3;
    const int scolz = ((lane & 7) ^ srow) * 8;   // pre-swizzled global source col
    const float scale = 0.125f;         // 1/sqrt(64)

    __shared__ alignas(16) unsigned short Qs[64][64];
    __shared__ alignas(16) unsigned short Ks[64][64];
    __shared__ alignas(16) unsigned short Vt[64][64];  // [d][k], swizzled
    __shared__ alignas(16) unsigned short Ps[64][64];

    const unsigned short* qbase = qkv + (size_t)(b * 1024 + qt * 64) * 3072 + h * 64;
#pragma unroll
    for (int i = 0; i < 2; i++) {
        int r0 = (i * 4 + wave) * 8;
        __builtin_amdgcn_global_load_lds(
            GCAST(&qbase[(size_t)(r0 + srow) * 3072 + scolz]),
            LCAST(&Qs[r0][0]), 16, 0, 0);
    }

    f32x4 O[4];
#pragma unroll
    for (int dt = 0; dt < 4; dt++) O[dt] = f32x4{0.f, 0.f, 0.f, 0.f};
    float m_run[4], l_run[4];
#pragma unroll
    for (int r = 0; r < 4; r++) { m_run[r] = -__builtin_inff(); l_run[r] = 0.f; }

    const int q_row_base = qt * 64 + wave * 16;

    for (int j = 0; j <= qt; j++) {
        __syncthreads();
        const unsigned short* kbase = qkv + (size_t)(b * 1024 + j * 64) * 3072 + 1024 + h * 64;
        const unsigned short* vbase = qkv + (size_t)(b * 1024 + j * 64) * 3072 + 2048 + h * 64;
#pragma unroll
        for (int i = 0; i < 2; i++) {
            int r0 = (i * 4 + wave) * 8;
            __builtin_amdgcn_global_load_lds(
                GCAST(&kbase[(size_t)(r0 + srow) * 3072 + scolz]),
                LCAST(&Ks[r0][0]), 16, 0, 0);
        }
#pragma unroll
        for (int i = 0; i < 4; i++) {
            int idx = tid + i * 256;
            int k = idx >> 4, c4 = (idx & 15) * 4;
            ushort4 vv = *(const ushort4*)&vbase[(size_t)k * 3072 + c4];
            char* vt = (char*)Vt;
            int klo = (k & 7) * 2;          // byte offset within 16B chunk
            int kch = (k >> 3) << 4;        // chunk byte base
            const unsigned short* vp = (const unsigned short*)&vv;
#pragma unroll
            for (int j2 = 0; j2 < 4; j2++) {
                int d = c4 + j2;
                *(unsigned short*)(vt + d * 128 + ((kch ^ ((d & 7) << 4)) | klo)) = vp[j2];
            }
        }
        __syncthreads();

        // S = Q K^T
        f32x4 Sc[4];
#pragma unroll
        for (int nt = 0; nt < 4; nt++) Sc[nt] = f32x4{0.f, 0.f, 0.f, 0.f};
        __builtin_amdgcn_s_setprio(1);
#pragma unroll
        for (int ks = 0; ks < 2; ks++) {
            bf16x8 aq = ldsw(&Qs[0][0], wave * 16 + l15, ks * 64 + quad * 16);
#pragma unroll
            for (int nt = 0; nt < 4; nt++) {
                bf16x8 bk = ldsw(&Ks[0][0], nt * 16 + l15, ks * 64 + quad * 16);
                Sc[nt] = __builtin_amdgcn_mfma_f32_16x16x32_bf16(aq, bk, Sc[nt], 0, 0, 0);
            }
        }
        __builtin_amdgcn_s_setprio(0);

#pragma unroll
        for (int nt = 0; nt < 4; nt++)
#pragma unroll
            for (int r = 0; r < 4; r++) Sc[nt][r] *= scale;

        if (j == qt) {   // causal mask only touches the diagonal tile
#pragma unroll
            for (int r = 0; r < 4; r++) {
                int qg = q_row_base + quad * 4 + r;
#pragma unroll
                for (int nt = 0; nt < 4; nt++) {
                    int kg = j * 64 + nt * 16 + l15;
                    if (kg > qg) Sc[nt][r] = -__builtin_inff();
                }
            }
        }

        float alpha[4];
#pragma unroll
        for (int r = 0; r < 4; r++) {
            float mx = -__builtin_inff();
#pragma unroll
            for (int nt = 0; nt < 4; nt++) mx = fmaxf(mx, Sc[nt][r]);
#pragma unroll
            for (int off = 1; off < 16; off <<= 1) mx = fmaxf(mx, __shfl_xor(mx, off));
            float mnew = fmaxf(m_run[r], mx);
            alpha[r] = __expf(m_run[r] - mnew);
            m_run[r] = mnew;
        }

#pragma unroll
        for (int r = 0; r < 4; r++) {
            float sum = 0.f;
#pragma unroll
            for (int nt = 0; nt < 4; nt++) {
                float p = __expf(Sc[nt][r] - m_run[r]);
                Sc[nt][r] = p;
                sum += p;
            }
#pragma unroll
            for (int off = 1; off < 16; off <<= 1) sum += __shfl_xor(sum, off);
            l_run[r] = l_run[r] * alpha[r] + sum;
        }

#pragma unroll
        for (int dt = 0; dt < 4; dt++)
#pragma unroll
            for (int r = 0; r < 4; r++) O[dt][r] *= alpha[r];

        {
            char* ps = (char*)Ps;
#pragma unroll
            for (int nt = 0; nt < 4; nt++)
#pragma unroll
                for (int r = 0; r < 4; r++) {
                    int row = wave * 16 + quad * 4 + r;
                    int col = nt * 16 + l15;
                    *(unsigned short*)(ps + row * 128 + ((col * 2) ^ ((row & 7) << 4)))
                        = f2bf(Sc[nt][r]);
                }
        }

        __builtin_amdgcn_s_setprio(1);
#pragma unroll
        for (int ks = 0; ks < 2; ks++) {
            bf16x8 ap = ldsw(&Ps[0][0], wave * 16 + l15, ks * 64 + quad * 16);
#pragma unroll
            for (int dt = 0; dt < 4; dt++) {
                bf16x8 bv = ldsw(&Vt[0][0], dt * 16 + l15, ks * 64 + quad * 16);
                O[dt] = __builtin_amdgcn_mfma_f32_16x16x32_bf16(ap, bv, O[dt], 0, 0, 0);
            }
        }
        __builtin_amdgcn_s_setprio(0);
    }

    unsigned short* obase = ctx + (size_t)(b * 1024 + qt * 64 + wave * 16) * 1024 + h * 64;
#pragma unroll
    for (int r = 0; r < 4; r++) {
        float inv = 1.f / l_run[r];
#pragma unroll
        for (int dt = 0; dt < 4; dt++)
            obase[(size_t)(quad * 4 + r) * 1024 + dt * 16 + l15] = f2bf(O[dt][r] * inv);
    }
}

// ---------------------------------------------------------------------------
// h = LayerNorm(h + r + r2) * w + b ; writes fp32 h and bf16 hb.
// ---------------------------------------------------------------------------
__global__ __launch_bounds__(256) void ln_residual_kernel(
    float* __restrict__ h, unsigned short* __restrict__ hb,
    const float* __restrict__ r, const float* __restrict__ r2,
    const float* __restrict__ w, const float* __restrict__ b)
{
    const int row = blockIdx.x;
    const int tid = threadIdx.x;
    const int lane = tid & 63, wave = tid >> 6;

    float4 hv = *(float4*)&h[(size_t)row * 1024 + tid * 4];
    float4 rv = *(const float4*)&r[(size_t)row * 1024 + tid * 4];
    float4 r2v = *(const float4*)&r2[(size_t)row * 1024 + tid * 4];
    float x0 = hv.x + rv.x + r2v.x, x1 = hv.y + rv.y + r2v.y;
    float x2 = hv.z + rv.z + r2v.z, x3 = hv.w + rv.w + r2v.w;

    float s  = x0 + x1 + x2 + x3;
    float s2 = x0 * x0 + x1 * x1 + x2 * x2 + x3 * x3;
#pragma unroll
    for (int off = 32; off >= 1; off >>= 1) {
        s  += __shfl_xor(s, off);
        s2 += __shfl_xor(s2, off);
    }
    __shared__ float ls[4], ls2[4];
    if (lane == 0) { ls[wave] = s; ls2[wave] = s2; }
    __syncthreads();
    s  = ls[0] + ls[1] + ls[2] + ls[3];
    s2 = ls2[0] + ls2[1] + ls2[2] + ls2[3];

    const float inv_n = 1.f / 1024.f;
    float mean = s * inv_n;
    float var  = s2 * inv_n - mean * mean;
    float rstd = rsqrtf(var + 1e-5f);

    float4 wv = *(const float4*)&w[tid * 4];
    float4 bv = *(const float4*)&b[tid * 4];
    float4 out;
    out.x = (x0 - mean) * rstd * wv.x + bv.x;
    out.y = (x1 - mean) * rstd * wv.y + bv.y;
    out.z = (x2 - mean) * rstd * wv.z + bv.z;
    out.w = (x3 - mean) * rstd * wv.w + bv.w;
    *(float4*)&h[(size_t)row * 1024 + tid * 4] = out;
    ushort4 ub;
    ub.x = f2bf(out.x); ub.y = f2bf(out.y); ub.z = f2bf(out.z); ub.w = f2bf(out.w);
    *(ushort4*)&hb[(size_t)row * 1024 + tid * 4] = ub;
}

__global__ __launch_bounds__(256) void copy_convert_kernel(
    const float* __restrict__ in, float* __restrict__ h, unsigned short* __restrict__ hb)
{
    int i = blockIdx.x * 256 + threadIdx.x;
    float4 v = ((const float4*)in)[i];
    ((float4*)h)[i] = v;
    ushort4 u;
    u.x = f2bf(v.x); u.y = f2bf(v.y); u.z = f2bf(v.z); u.w = f2bf(v.w);
    ((ushort4*)hb)[i] = u;
}

// ---------------------------------------------------------------------------
extern "C" void kernel_launch(void* const* d_in, const int* in_sizes, int n_in,
                              void* d_out, int out_size, void* d_ws, size_t ws_size,
                              hipStream_t stream)
{
    const float* x     = (const float*)d_in[0];
    const float* qkv_w = (const float*)d_in[1];
    const float* qkv_b = (const float*)d_in[2];
    const float* out_w = (const float*)d_in[3];
    const float* out_b = (const float*)d_in[4];
    const float* w1    = (const float*)d_in[5];
    const float* b1    = (const float*)d_in[6];
    const float* w2    = (const float*)d_in[7];
    const float* b2    = (const float*)d_in[8];
    const float* ln1w  = (const float*)d_in[9];
    const float* ln1b  = (const float*)d_in[10];
    const float* ln2w  = (const float*)d_in[11];
    const float* ln2b  = (const float*)d_in[12];

    float* h = (float*)d_out;                       // fp32 residual stream [4096,1024]
    char* ws = (char*)d_ws;
    // layout: qkv bf16 [4096,3072] aliased with t bf16 [4096,4096]
    unsigned short* qkvb = (unsigned short*)ws;
    unsigned short* tb   = (unsigned short*)ws;
    unsigned short* ctxb = (unsigned short*)(ws + 33554432);           // [4096,1024] bf16
    unsigned short* hb   = (unsigned short*)(ws + 33554432 + 8388608); // [4096,1024] bf16
    unsigned short* wbf  = (unsigned short*)(ws + 50331648);           // 12.58M bf16 weights
    float*          r    = (float*)(ws + 75497472);                    // [4096,1024] fp32
    float*          r2   = (float*)(ws + 92274688);                    // [4096,1024] fp32

    unsigned short* wb_qkv = wbf;
    unsigned short* wb_out = wbf + 3145728;
    unsigned short* wb_w1  = wbf + 4194304;
    unsigned short* wb_w2  = wbf + 8388608;

    copy_convert_kernel<<<4096, 256, 0, stream>>>(x, h, hb);

    for (int l = 0; l < 16; l++) {
        convert_weights_kernel<<<12288, 256, 0, stream>>>(
            qkv_w + (size_t)l * 3145728, out_w + (size_t)l * 1048576,
            w1 + (size_t)l * 4194304, w2 + (size_t)l * 4194304, wbf);

        // qkv = hb @ Wqkv^T + b           [4096,3072] bf16 (256^2 pipeline)
        gemm256_kernel<<<dim3(12, 16), 512, 0, stream>>>(
            hb, wb_qkv, qkv_b + (size_t)l * 3072, qkvb, 3072, 1024, 0);
        // ctx = causal_attention(qkv)     [4096,1024] bf16
        attn_kernel<<<dim3(16, 64), 256, 0, stream>>>(qkvb, ctxb);
        // r + r2 = ctx @ Wout^T + b       fp32 partials (split-K=2)
        gemm_splitk_kernel<<<dim3(8, 32, 2), 256, 0, stream>>>(
            ctxb, wb_out, out_b + (size_t)l * 1024, r, r2, 1024, 1024);
        // h = LN1(h + r + r2); hb = bf16(h)
        ln_residual_kernel<<<4096, 256, 0, stream>>>(
            h, hb, r, r2, ln1w + (size_t)l * 1024, ln1b + (size_t)l * 1024);
        // t = relu(hb @ W1^T + b1)        [4096,4096] bf16 (256^2 pipeline)
        gemm256_kernel<<<dim3(16, 16), 512, 0, stream>>>(
            hb, wb_w1, b1 + (size_t)l * 4096, tb, 4096, 1024, 1);
        // r + r2 = t @ W2^T + b2          fp32 partials (split-K=2)
        gemm_splitk_kernel<<<dim3(8, 32, 2), 256, 0, stream>>>(
            tb, wb_w2, b2 + (size_t)l * 1024, r, r2, 1024, 4096);
        // h = LN2(h + r + r2); hb = bf16(h)
        ln_residual_kernel<<<4096, 256, 0, stream>>>(
            h, hb, r, r2, ln2w + (size_t)l * 1024, ln2b + (size_t)l * 1024);
    }
}